// Round 15
// baseline (884.080 us; speedup 1.0000x reference)
//
#include <hip/hip_runtime.h>
#include <hip/hip_bf16.h>

constexpr int Bc = 16, Nc = 400, Fc = 64, Tc = 12, NHc = 4, HDc = 16;
constexpr int NN = Nc * Nc;

// ---------------- CSR row pointers from sorted src ----------------
__global__ void k_rowptr(const int* __restrict__ src, int E, int* __restrict__ rowp) {
    for (int e = threadIdx.x; e < E; e += blockDim.x) {
        int s = src[e];
        if (e == 0 || src[e - 1] != s) rowp[s] = e;
    }
    if (threadIdx.x == 0) rowp[Nc] = E;
}

// ---------------- transpose wadj (per batch) ----------------
__global__ void k_transpose(const float* __restrict__ in, float* __restrict__ out) {
    __shared__ float tile[32][33];
    int b = blockIdx.z;
    int x0 = blockIdx.x * 32, y0 = blockIdx.y * 32;
    const float* inb = in + (size_t)b * NN;
    float* outb = out + (size_t)b * NN;
    for (int j = threadIdx.y; j < 32; j += 8) {
        int y = y0 + j, x = x0 + threadIdx.x;
        if (y < Nc && x < Nc) tile[j][threadIdx.x] = inb[y * Nc + x];
    }
    __syncthreads();
    for (int j = threadIdx.y; j < 32; j += 8) {
        int y = x0 + j, x = y0 + threadIdx.x;
        if (y < Nc && x < Nc) outb[y * Nc + x] = tile[threadIdx.x][j];
    }
}

// ---------------- per-edge coefficients (float4 dot): cf1 = wadj*sc, cf2 = (wadj@wadj)*sc ----------------
__global__ void k_w2ec(const float* __restrict__ wadj, const float* __restrict__ wadjT,
                       const int* __restrict__ src, const int* __restrict__ dst,
                       const int* __restrict__ rowp, int E,
                       float* __restrict__ cf1, float* __restrict__ cf2) {
    int widx = (blockIdx.x * blockDim.x + threadIdx.x) >> 6;
    int lane = threadIdx.x & 63;
    if (widx >= Bc * E) return;
    int b = widx / E, e = widx % E;
    int i = src[e], j = dst[e];
    const float* ra = wadj + (size_t)b * NN + (size_t)i * Nc;
    const float* rb = wadjT + (size_t)b * NN + (size_t)j * Nc;
    float s = 0.f;
    for (int k0 = lane * 4; k0 < Nc; k0 += 256) {
        float4 a4 = *(const float4*)(ra + k0);
        float4 b4 = *(const float4*)(rb + k0);
        s = fmaf(a4.x, b4.x, s);
        s = fmaf(a4.y, b4.y, s);
        s = fmaf(a4.z, b4.z, s);
        s = fmaf(a4.w, b4.w, s);
    }
    for (int off = 32; off; off >>= 1) s += __shfl_xor(s, off, 64);
    if (lane == 0) {
        float deg = (float)(rowp[i + 1] - rowp[i] - 1);
        float sc = (j == i) ? 1.f : 1.f / (deg + 1e-10f);
        cf1[widx] = ra[j] * sc;
        cf2[widx] = s * sc;
    }
}

// ---------------- spatial QKV; sqkv layout (bt, sel, h, n, d16) ----------------
__global__ __launch_bounds__(384) void k_qkv3(const float* __restrict__ x,
    const float* __restrict__ wq, const float* __restrict__ bq,
    const float* __restrict__ wk, const float* __restrict__ bk,
    const float* __restrict__ wv, const float* __restrict__ bv,
    float* __restrict__ sqkv) {
    __shared__ float xs[8 * 768];
    int blk = blockIdx.x;
    int b = blk / 50, nch = blk % 50;
    int n0 = nch * 8;
    const float* xp = x + ((long)b * Nc + n0) * 768;
    for (int i = threadIdx.x; i < 1536; i += 384)
        ((float4*)xs)[i] = ((const float4*)xp)[i];
    __syncthreads();
    int wid = threadIdx.x >> 6, lane = threadIdx.x & 63;
    int sel = wid % 3, half = wid / 3;
    int hh = lane >> 4, dd = lane & 15;
    const float* W = sel == 0 ? wq : sel == 1 ? wk : wv;
    const float* Bb = sel == 0 ? bq : sel == 1 ? bk : bv;
    float wr[64];
#pragma unroll
    for (int f = 0; f < 64; ++f) wr[f] = W[f * 64 + lane];
    float bias = Bb[lane];
    for (int nl = half * 4; nl < half * 4 + 4; ++nl) {
        int n = n0 + nl;
        const float* xrow = xs + nl * 768;
        for (int t0 = 0; t0 < 12; t0 += 4) {
            float a[4] = {bias, bias, bias, bias};
#pragma unroll
            for (int f = 0; f < 64; ++f) {
                float w = wr[f];
                const float* xq = xrow + f * 12 + t0;
                a[0] = fmaf(xq[0], w, a[0]);
                a[1] = fmaf(xq[1], w, a[1]);
                a[2] = fmaf(xq[2], w, a[2]);
                a[3] = fmaf(xq[3], w, a[3]);
            }
#pragma unroll
            for (int i = 0; i < 4; ++i) {
                long bt = (long)b * 12 + t0 + i;
                sqkv[(((bt * 3 + sel) * NHc + hh) * Nc + n) * HDc + dd] = a[i];
            }
        }
    }
}

// ---------------- spatial attention: 200-query blocks (2 per bth), dbuf tiles ----------------
__global__ __launch_bounds__(256) void k_sattn6(const float* __restrict__ sqkv,
                                                float* __restrict__ Os) {
    constexpr int KT = 80;                      // 400 = 5*80
    __shared__ float Kb[2][KT * 16];
    __shared__ float Vb[2][KT * 16];
    int blk = blockIdx.x;                       // 1536 = 768 bth * 2 halves
    int half = blk & 1;
    int bth = blk >> 1;
    int h = bth & 3;
    int bt = bth >> 2;
    const float* Qb = sqkv + (((long)bt * 3 + 0) * NHc + h) * (Nc * HDc);
    const float* Kg = sqkv + (((long)bt * 3 + 1) * NHc + h) * (Nc * HDc);
    const float* Vg = sqkv + (((long)bt * 3 + 2) * NHc + h) * (Nc * HDc);
    int tid = threadIdx.x;
    // prologue: stage tile 0 (contiguous float4 streams)
    for (int i = tid; i < KT * 8; i += 256) {
        if (i < KT * 4) ((float4*)Kb[0])[i] = ((const float4*)Kg)[i];
        else            ((float4*)Vb[0])[i - KT * 4] = ((const float4*)Vg)[i - KT * 4];
    }
    bool act = tid < 200;
    int nq = half * 200 + tid;
    float q[16];
    if (act) {
        constexpr float SC = 0.25f * 1.44269504f;   // fold scale + log2(e)
#pragma unroll
        for (int d = 0; d < 16; ++d) q[d] = Qb[nq * 16 + d] * SC;
    }
    float m = -INFINITY, l = 0.f, acc[16];
#pragma unroll
    for (int d = 0; d < 16; ++d) acc[d] = 0.f;
    __syncthreads();
    for (int t = 0; t < 5; ++t) {
        int cur = t & 1;
        if (t < 4) {
            const float4* Kn = (const float4*)(Kg + (t + 1) * KT * 16);
            const float4* Vn = (const float4*)(Vg + (t + 1) * KT * 16);
            for (int i = tid; i < KT * 8; i += 256) {
                if (i < KT * 4) ((float4*)Kb[cur ^ 1])[i] = Kn[i];
                else            ((float4*)Vb[cur ^ 1])[i - KT * 4] = Vn[i - KT * 4];
            }
        }
        if (act) {
            for (int c = 0; c < KT; c += 16) {
                float s[16];
                float tm = -INFINITY;
#pragma unroll
                for (int kk = 0; kk < 16; ++kk) {
                    const float* kvp = &Kb[cur][(c + kk) * 16];
                    float d0 = 0.f;
#pragma unroll
                    for (int d = 0; d < 16; ++d) d0 = fmaf(q[d], kvp[d], d0);
                    s[kk] = d0;
                    tm = fmaxf(tm, d0);
                }
                if (tm > m) {
                    float corr = __builtin_amdgcn_exp2f(m - tm);
                    l *= corr;
#pragma unroll
                    for (int d = 0; d < 16; ++d) acc[d] *= corr;
                    m = tm;
                }
#pragma unroll
                for (int kk = 0; kk < 16; ++kk) {
                    float p = __builtin_amdgcn_exp2f(s[kk] - m);
                    l += p;
                    const float* vv = &Vb[cur][(c + kk) * 16];
#pragma unroll
                    for (int d = 0; d < 16; ++d) acc[d] = fmaf(p, vv[d], acc[d]);
                }
            }
        }
        __syncthreads();
    }
    if (act) {
        float inv = 1.f / l;
        float* op = Os + ((long)bt * Nc + nq) * 64 + h * 16;
#pragma unroll
        for (int d = 0; d < 16; ++d) op[d] = acc[d] * inv;
    }
}

// ---------------- row-64 projection via wave-broadcast GEMM ----------------
__global__ __launch_bounds__(256) void k_proj64b(const float* __restrict__ X,
    const float* __restrict__ W, const float* __restrict__ bias,
    float* __restrict__ Y) {
    __shared__ float xs[64 * 64];
    long r0 = (long)blockIdx.x * 64;
    const float* xp = X + r0 * 64;
    for (int i = threadIdx.x; i < 1024; i += 256)
        ((float4*)xs)[i] = ((const float4*)xp)[i];
    int wid = threadIdx.x >> 6, lane = threadIdx.x & 63;
    float wr[64];
#pragma unroll
    for (int f = 0; f < 64; ++f) wr[f] = W[f * 64 + lane];
    float bv = bias[lane];
    __syncthreads();
    for (int g = 0; g < 4; ++g) {
        int r = wid * 16 + g * 4;
        float a[4] = {bv, bv, bv, bv};
#pragma unroll
        for (int f = 0; f < 64; ++f) {
            float w = wr[f];
            a[0] = fmaf(xs[(r + 0) * 64 + f], w, a[0]);
            a[1] = fmaf(xs[(r + 1) * 64 + f], w, a[1]);
            a[2] = fmaf(xs[(r + 2) * 64 + f], w, a[2]);
            a[3] = fmaf(xs[(r + 3) * 64 + f], w, a[3]);
        }
#pragma unroll
        for (int i = 0; i < 4; ++i) Y[(r0 + r + i) * 64 + lane] = a[i];
    }
}

// ---------------- dual no-bias projection: G1 = X@W1, G2 = X@W2 ----------------
__global__ __launch_bounds__(512) void k_proj2(const float* __restrict__ X,
    const float* __restrict__ W1, const float* __restrict__ W2,
    float* __restrict__ G1, float* __restrict__ G2) {
    __shared__ float xs[64 * 64];
    long r0 = (long)blockIdx.x * 64;
    const float* xp = X + r0 * 64;
    for (int i = threadIdx.x; i < 1024; i += 512)
        ((float4*)xs)[i] = ((const float4*)xp)[i];
    int wid = threadIdx.x >> 6, lane = threadIdx.x & 63;
    const float* W = (wid & 4) ? W2 : W1;
    float* G = (wid & 4) ? G2 : G1;
    int w4 = wid & 3;
    float wr[64];
#pragma unroll
    for (int f = 0; f < 64; ++f) wr[f] = W[f * 64 + lane];
    __syncthreads();
    for (int g = 0; g < 4; ++g) {
        int r = w4 * 16 + g * 4;
        float a[4] = {0.f, 0.f, 0.f, 0.f};
#pragma unroll
        for (int f = 0; f < 64; ++f) {
            float w = wr[f];
            a[0] = fmaf(xs[(r + 0) * 64 + f], w, a[0]);
            a[1] = fmaf(xs[(r + 1) * 64 + f], w, a[1]);
            a[2] = fmaf(xs[(r + 2) * 64 + f], w, a[2]);
            a[3] = fmaf(xs[(r + 3) * 64 + f], w, a[3]);
        }
#pragma unroll
        for (int i = 0; i < 4; ++i) G[(r0 + r + i) * 64 + lane] = a[i];
    }
}

// ---------------- sparse gather + sigmoid (no matmul, no LDS) ----------------
__global__ __launch_bounds__(256) void k_gath(const float* __restrict__ G1,
    const float* __restrict__ G2, const float* __restrict__ cf1,
    const float* __restrict__ cf2, const int* __restrict__ rowp,
    const int* __restrict__ dst, const float* __restrict__ thA,
    const float* __restrict__ thB, int E, float* __restrict__ Y) {
    int blk = blockIdx.x;
    int bt = blk % 192;
    int n0 = (blk / 192) * 4;
    int b = bt / Tc;
    int nl = threadIdx.x >> 6, lane = threadIdx.x & 63;
    int n = n0 + nl;
    const float* g1 = G1 + (long)bt * Nc * 64;
    const float* g2 = G2 + (long)bt * Nc * 64;
    const float* c1p = cf1 + (size_t)b * E;
    const float* c2p = cf2 + (size_t)b * E;
    int e0 = rowp[n], e1 = rowp[n + 1];
    float a1 = 0.f, a2 = 0.f;
    for (int e = e0; e < e1; ++e) {
        int j = dst[e] * 64 + lane;
        a1 = fmaf(c1p[e], g1[j], a1);
        a2 = fmaf(c2p[e], g2[j], a2);
    }
    float acc = thA[n] * a1 + thB[n] * a2;
    Y[((long)bt * Nc + n) * 64 + lane] = 1.f / (1.f + __expf(-acc));
}

// ---------------- temporal MHA: dedup scores, padded qs; ta in (B,N,T,F) ----------------
__global__ __launch_bounds__(384) void k_tattn3(const float* __restrict__ x,
    const float* __restrict__ wq, const float* __restrict__ bq,
    const float* __restrict__ wk, const float* __restrict__ bk,
    const float* __restrict__ wv, const float* __restrict__ bv,
    const float* __restrict__ wo, const float* __restrict__ bo,
    float* __restrict__ ta) {
    constexpr int QS = 193;
    __shared__ float xs_ol[3072];
    __shared__ float qs[48 * QS];
    float* xs = xs_ol;
    float* ol = xs_ol;
    int blk = blockIdx.x;
    int b = blk / 100, nch = blk % 100;
    int n0 = nch * 4;
    const float* xp = x + ((long)b * Nc + n0) * 768;
    for (int i = threadIdx.x; i < 768; i += 384)
        ((float4*)xs)[i] = ((const float4*)xp)[i];
    __syncthreads();
    int wid = threadIdx.x >> 6, lane = threadIdx.x & 63;
    {
        int sel = wid % 3, half = wid / 3;
        const float* W = sel == 0 ? wq : sel == 1 ? wk : wv;
        const float* Bb = sel == 0 ? bq : sel == 1 ? bk : bv;
        float wr[64];
#pragma unroll
        for (int f = 0; f < 64; ++f) wr[f] = W[f * 64 + lane];
        float bias = Bb[lane];
        for (int nl = half * 2; nl < half * 2 + 2; ++nl) {
            const float* xrow = xs + nl * 768;
            for (int t0 = 0; t0 < 12; t0 += 4) {
                float a[4] = {bias, bias, bias, bias};
#pragma unroll
                for (int f = 0; f < 64; ++f) {
                    float w = wr[f];
                    const float* xq = xrow + f * 12 + t0;
                    a[0] = fmaf(xq[0], w, a[0]);
                    a[1] = fmaf(xq[1], w, a[1]);
                    a[2] = fmaf(xq[2], w, a[2]);
                    a[3] = fmaf(xq[3], w, a[3]);
                }
#pragma unroll
                for (int i = 0; i < 4; ++i)
                    qs[(nl * 12 + t0 + i) * QS + sel * 64 + lane] = a[i];
            }
        }
    }
    __syncthreads();
    {
        int triple = threadIdx.x >> 1, dh = threadIdx.x & 1;
        int nl = triple / 48, r2 = triple % 48;
        int t = r2 >> 2, h = r2 & 3;
        const float* qv = qs + (nl * 12 + t) * QS + h * 16;
        float s[12];
        float mx = -INFINITY;
#pragma unroll
        for (int k = 0; k < 12; ++k) {
            const float* kv = qs + (nl * 12 + k) * QS + 64 + h * 16;
            float a0 = 0.f;
#pragma unroll
            for (int dd = 0; dd < 16; ++dd) a0 = fmaf(qv[dd], kv[dd], a0);
            s[k] = a0 * 0.25f;
            mx = fmaxf(mx, s[k]);
        }
        float l = 0.f;
#pragma unroll
        for (int k = 0; k < 12; ++k) { s[k] = __expf(s[k] - mx); l += s[k]; }
        float inv = 1.f / l;
#pragma unroll
        for (int dd = 0; dd < 8; ++dd) {
            int d = dh * 8 + dd;
            float o = 0.f;
#pragma unroll
            for (int k = 0; k < 12; ++k)
                o = fmaf(s[k], qs[(nl * 12 + k) * QS + 128 + h * 16 + d], o);
            ol[(nl * 12 + t) * 64 + h * 16 + d] = o * inv;
        }
    }
    __syncthreads();
    {
        float wr[64];
#pragma unroll
        for (int f = 0; f < 64; ++f) wr[f] = wo[f * 64 + lane];
        float ob = bo[lane];
        for (int g = 0; g < 2; ++g) {
            int r = wid * 8 + g * 4;
            float a[4] = {ob, ob, ob, ob};
#pragma unroll
            for (int f = 0; f < 64; ++f) {
                float w = wr[f];
                a[0] = fmaf(ol[(r + 0) * 64 + f], w, a[0]);
                a[1] = fmaf(ol[(r + 1) * 64 + f], w, a[1]);
                a[2] = fmaf(ol[(r + 2) * 64 + f], w, a[2]);
                a[3] = fmaf(ol[(r + 3) * 64 + f], w, a[3]);
            }
#pragma unroll
            for (int i = 0; i < 4; ++i) {
                int rr = r + i;
                int nl = rr / 12, t = rr % 12;
                ta[(((long)b * Nc + n0 + nl) * 12 + t) * 64 + lane] = a[i];
            }
        }
    }
}

// ---------------- neighborhood max (incl self); XCD-swizzled ----------------
__global__ __launch_bounds__(256) void k_segmax(const float* __restrict__ h,
    const int* __restrict__ rowp, const int* __restrict__ dst, float* __restrict__ Y) {
    int blk = blockIdx.x;
    int bt = blk % 192;
    int n0 = (blk / 192) * 4;
    int nl = threadIdx.x >> 6, f = threadIdx.x & 63;
    int n = n0 + nl;
    int e0 = rowp[n], e1 = rowp[n + 1];
    float m = -INFINITY;
    const float* hb = h + (long)bt * Nc * 64;
    for (int e = e0; e < e1; ++e) m = fmaxf(m, hb[dst[e] * 64 + f]);
    Y[((long)bt * Nc + n) * 64 + f] = m;
}

// ---------------- fused gated temporal conv + mask + residual relu + layernorm ----------------
__global__ __launch_bounds__(256) void k_gatedfinal(const float* __restrict__ ta,
    const float* __restrict__ tcw, const float* __restrict__ tcb,
    const float* __restrict__ gcw, const float* __restrict__ gcb,
    const float* __restrict__ mean2, const float* __restrict__ x,
    const float* __restrict__ mw, const float* __restrict__ md,
    const float* __restrict__ lng, const float* __restrict__ lnb,
    const int* __restrict__ maskp, float* __restrict__ out) {
    __shared__ float wl[192 * 65];       // [(ic*3+dt)*65 + o]
    __shared__ float tal[4][64 * 13];    // [ic*13 + t]
    int wave = threadIdx.x >> 6, lane = threadIdx.x & 63;
    int bn = blockIdx.x * 4 + wave;
    for (int idx = threadIdx.x; idx < 64 * 192; idx += 256) {
        int o = idx / 192, r = idx % 192;
        wl[r * 65 + o] = tcw[idx];
    }
    {
        const float* tr = ta + (long)bn * 768;
        for (int i = lane; i < 768; i += 64) {
            int t = i >> 6, f = i & 63;
            tal[wave][f * 13 + t] = tr[i];
        }
    }
    __syncthreads();
    int o = lane;
    float acc_t[12], acc_g[12];
#pragma unroll
    for (int t = 0; t < 12; ++t) acc_t[t] = tcb[o];
    for (int ic = 0; ic < 64; ++ic) {
        float xe[14];
        xe[0] = 0.f; xe[13] = 0.f;
#pragma unroll
        for (int t = 0; t < 12; ++t) xe[t + 1] = tal[wave][ic * 13 + t];
        float w0 = wl[(ic * 3 + 0) * 65 + o];
        float w1 = wl[(ic * 3 + 1) * 65 + o];
        float w2 = wl[(ic * 3 + 2) * 65 + o];
#pragma unroll
        for (int t = 0; t < 12; ++t)
            acc_t[t] += xe[t] * w0 + xe[t + 1] * w1 + xe[t + 2] * w2;
    }
    __syncthreads();
    for (int idx = threadIdx.x; idx < 64 * 192; idx += 256) {
        int o2 = idx / 192, r = idx % 192;
        wl[r * 65 + o2] = gcw[idx];
    }
    __syncthreads();
#pragma unroll
    for (int t = 0; t < 12; ++t) acc_g[t] = gcb[o];
    for (int ic = 0; ic < 64; ++ic) {
        float xe[14];
        xe[0] = 0.f; xe[13] = 0.f;
#pragma unroll
        for (int t = 0; t < 12; ++t) xe[t + 1] = tal[wave][ic * 13 + t];
        float w0 = wl[(ic * 3 + 0) * 65 + o];
        float w1 = wl[(ic * 3 + 1) * 65 + o];
        float w2 = wl[(ic * 3 + 2) * 65 + o];
#pragma unroll
        for (int t = 0; t < 12; ++t)
            acc_g[t] += xe[t] * w0 + xe[t + 1] * w1 + xe[t + 2] * w2;
    }
    int b = bn / Nc, n = bn % Nc;
    float maskf = maskp[0] ? (mw[bn] * md[bn]) : 1.f;
    const float* xrow = x + (long)bn * 768 + o * 12;   // (B,N,F,T): 12 contiguous t's
    float4 xa = *(const float4*)(xrow);
    float4 xb = *(const float4*)(xrow + 4);
    float4 xc = *(const float4*)(xrow + 8);
    float xv[12] = {xa.x, xa.y, xa.z, xa.w, xb.x, xb.y, xb.z, xb.w, xc.x, xc.y, xc.z, xc.w};
    float y[12];
#pragma unroll
    for (int t = 0; t < 12; ++t) {
        float g = acc_t[t] * (1.f / (1.f + __expf(-acc_g[t])));
        long base = ((long)(b * Tc + t) * Nc + n) * 64;
        float v = mean2[base + o] * maskf + g;
        float r = fmaxf(v + xv[t], 0.f);
        float s = r;
        for (int off = 32; off; off >>= 1) s += __shfl_xor(s, off, 64);
        float mu = s * (1.f / 64.f);
        float d = r - mu;
        float vs = d * d;
        for (int off = 32; off; off >>= 1) vs += __shfl_xor(vs, off, 64);
        float var = vs * (1.f / 64.f);
        y[t] = d * rsqrtf(var + 1e-5f) * lng[o] + lnb[o];
    }
    float* orow = out + (long)bn * 768 + o * 12;
    *(float4*)(orow)     = make_float4(y[0], y[1], y[2], y[3]);
    *(float4*)(orow + 4) = make_float4(y[4], y[5], y[6], y[7]);
    *(float4*)(orow + 8) = make_float4(y[8], y[9], y[10], y[11]);
}

extern "C" void kernel_launch(void* const* d_in, const int* in_sizes, int n_in,
                              void* d_out, int out_size, void* d_ws, size_t ws_size,
                              hipStream_t stream) {
    const float* x    = (const float*)d_in[0];
    const float* wadj = (const float*)d_in[1];
    const float* mw   = (const float*)d_in[2];
    const float* md   = (const float*)d_in[3];
    const float* th1  = (const float*)d_in[4];
    const float* th2  = (const float*)d_in[5];
    const float* th3  = (const float*)d_in[6];
    const float* th4  = (const float*)d_in[7];
    const float* gw1a = (const float*)d_in[8];
    const float* gw1b = (const float*)d_in[9];
    const float* gw2a = (const float*)d_in[10];
    const float* gw2b = (const float*)d_in[11];
    const float* mpw  = (const float*)d_in[12];
    const float* mpb  = (const float*)d_in[13];
    const float* tcw  = (const float*)d_in[14];
    const float* tcb  = (const float*)d_in[15];
    const float* gcw  = (const float*)d_in[16];
    const float* gcb  = (const float*)d_in[17];
    const float* sqw  = (const float*)d_in[18]; const float* sqb = (const float*)d_in[19];
    const float* skw  = (const float*)d_in[20]; const float* skb = (const float*)d_in[21];
    const float* svw  = (const float*)d_in[22]; const float* svb = (const float*)d_in[23];
    const float* sow  = (const float*)d_in[24]; const float* sob = (const float*)d_in[25];
    const float* tqw  = (const float*)d_in[26]; const float* tqb = (const float*)d_in[27];
    const float* tkw  = (const float*)d_in[28]; const float* tkb = (const float*)d_in[29];
    const float* tvw  = (const float*)d_in[30]; const float* tvb = (const float*)d_in[31];
    const float* tow  = (const float*)d_in[32]; const float* tob = (const float*)d_in[33];
    const float* lng  = (const float*)d_in[34]; const float* lnb = (const float*)d_in[35];
    const int* eidx   = (const int*)d_in[37];
    const int* maskp  = (const int*)d_in[38];
    int E = in_sizes[37] / 2;
    const int* esrc = eidx;
    const int* edst = eidx + E;

    const long SZ = (long)Bc * Tc * Nc * 64;             // 4,915,200
    float* ws = (float*)d_ws;
    // persistent region
    float* sqkv  = ws;                                   // [0,3SZ)
    float* Os    = ws + 3 * SZ;                          // [3SZ,4SZ); later mean2
    float* sa    = ws + 4 * SZ;
    float* ta    = ws + 5 * SZ;
    float* wadjT = ws + 6 * SZ;                          // B*N*N
    float* cf1   = wadjT + (long)Bc * NN;                // B*E
    float* cf2   = cf1 + (long)Bc * E;                   // B*E
    int*   rowp  = (int*)(cf2 + (long)Bc * E);           // N+1
    // phase aliases (sqkv region, dead after k_sattn6)
    float* g1    = ws;
    float* g2    = ws + SZ;
    float* mean1 = ws + 2 * SZ;
    float* hbuf  = ws;                                   // after g1 dead
    float* maxp  = ws + SZ;                              // after g2 dead
    float* g1b   = ws;                                   // after hbuf dead
    float* g2b   = ws + 2 * SZ;                          // after mean1 dead
    float* mean2 = Os;                                   // Os dead after so-proj

    hipLaunchKernelGGL(k_rowptr, dim3(1), dim3(256), 0, stream, esrc, E, rowp);
    hipLaunchKernelGGL(k_transpose, dim3(13, 13, Bc), dim3(32, 8), 0, stream, wadj, wadjT);
    int w2blocks = (Bc * E + 3) / 4;
    hipLaunchKernelGGL(k_w2ec, dim3(w2blocks), dim3(256), 0, stream, wadj, wadjT, esrc, edst, rowp, E, cf1, cf2);
    hipLaunchKernelGGL(k_qkv3, dim3(Bc * 50), dim3(384), 0, stream, x, sqw, sqb, skw, skb, svw, svb, sqkv);
    hipLaunchKernelGGL(k_sattn6, dim3(Bc * Tc * NHc * 2), dim3(256), 0, stream, sqkv, Os);
    hipLaunchKernelGGL(k_proj64b, dim3(1200), dim3(256), 0, stream, Os, sow, sob, sa);
    hipLaunchKernelGGL(k_tattn3, dim3(Bc * 100), dim3(384), 0, stream, x, tqw, tqb, tkw, tkb, tvw, tvb, tow, tob, ta);
    hipLaunchKernelGGL(k_proj2, dim3(1200), dim3(512), 0, stream, sa, gw1a, gw1b, g1, g2);
    hipLaunchKernelGGL(k_gath, dim3(19200), dim3(256), 0, stream, g1, g2, cf1, cf2, rowp, edst, th1, th2, E, mean1);
    hipLaunchKernelGGL(k_proj64b, dim3(1200), dim3(256), 0, stream, mean1, mpw, mpb, hbuf);
    hipLaunchKernelGGL(k_segmax, dim3(19200), dim3(256), 0, stream, hbuf, rowp, edst, maxp);
    hipLaunchKernelGGL(k_proj2, dim3(1200), dim3(512), 0, stream, maxp, gw2a, gw2b, g1b, g2b);
    hipLaunchKernelGGL(k_gath, dim3(19200), dim3(256), 0, stream, g1b, g2b, cf1, cf2, rowp, edst, th3, th4, E, mean2);
    hipLaunchKernelGGL(k_gatedfinal, dim3(1600), dim3(256), 0, stream, ta, tcw, tcb, gcw, gcb,
                       mean2, x, mw, md, lng, lnb, maskp, (float*)d_out);
}

// Round 16
// 846.217 us; speedup vs baseline: 1.0447x; 1.0447x over previous
//
#include <hip/hip_runtime.h>
#include <hip/hip_bf16.h>

constexpr int Bc = 16, Nc = 400, Fc = 64, Tc = 12, NHc = 4, HDc = 16;
constexpr int NN = Nc * Nc;

// ---------------- CSR row pointers from sorted src ----------------
__global__ void k_rowptr(const int* __restrict__ src, int E, int* __restrict__ rowp) {
    for (int e = threadIdx.x; e < E; e += blockDim.x) {
        int s = src[e];
        if (e == 0 || src[e - 1] != s) rowp[s] = e;
    }
    if (threadIdx.x == 0) rowp[Nc] = E;
}

// ---------------- transpose wadj (per batch) ----------------
__global__ void k_transpose(const float* __restrict__ in, float* __restrict__ out) {
    __shared__ float tile[32][33];
    int b = blockIdx.z;
    int x0 = blockIdx.x * 32, y0 = blockIdx.y * 32;
    const float* inb = in + (size_t)b * NN;
    float* outb = out + (size_t)b * NN;
    for (int j = threadIdx.y; j < 32; j += 8) {
        int y = y0 + j, x = x0 + threadIdx.x;
        if (y < Nc && x < Nc) tile[j][threadIdx.x] = inb[y * Nc + x];
    }
    __syncthreads();
    for (int j = threadIdx.y; j < 32; j += 8) {
        int y = x0 + j, x = y0 + threadIdx.x;
        if (y < Nc && x < Nc) outb[y * Nc + x] = tile[threadIdx.x][j];
    }
}

// ---------------- per-edge coefficients (float4 dot): cf1 = wadj*sc, cf2 = (wadj@wadj)*sc ----------------
__global__ void k_w2ec(const float* __restrict__ wadj, const float* __restrict__ wadjT,
                       const int* __restrict__ src, const int* __restrict__ dst,
                       const int* __restrict__ rowp, int E,
                       float* __restrict__ cf1, float* __restrict__ cf2) {
    int widx = (blockIdx.x * blockDim.x + threadIdx.x) >> 6;
    int lane = threadIdx.x & 63;
    if (widx >= Bc * E) return;
    int b = widx / E, e = widx % E;
    int i = src[e], j = dst[e];
    const float* ra = wadj + (size_t)b * NN + (size_t)i * Nc;
    const float* rb = wadjT + (size_t)b * NN + (size_t)j * Nc;
    float s = 0.f;
    for (int k0 = lane * 4; k0 < Nc; k0 += 256) {
        float4 a4 = *(const float4*)(ra + k0);
        float4 b4 = *(const float4*)(rb + k0);
        s = fmaf(a4.x, b4.x, s);
        s = fmaf(a4.y, b4.y, s);
        s = fmaf(a4.z, b4.z, s);
        s = fmaf(a4.w, b4.w, s);
    }
    for (int off = 32; off; off >>= 1) s += __shfl_xor(s, off, 64);
    if (lane == 0) {
        float deg = (float)(rowp[i + 1] - rowp[i] - 1);
        float sc = (j == i) ? 1.f : 1.f / (deg + 1e-10f);
        cf1[widx] = ra[j] * sc;
        cf2[widx] = s * sc;
    }
}

// ---------------- spatial QKV; sqkv layout (bt, sel, h, n, d16) ----------------
__global__ __launch_bounds__(384) void k_qkv3(const float* __restrict__ x,
    const float* __restrict__ wq, const float* __restrict__ bq,
    const float* __restrict__ wk, const float* __restrict__ bk,
    const float* __restrict__ wv, const float* __restrict__ bv,
    float* __restrict__ sqkv) {
    __shared__ float xs[8 * 768];
    int blk = blockIdx.x;
    int b = blk / 50, nch = blk % 50;
    int n0 = nch * 8;
    const float* xp = x + ((long)b * Nc + n0) * 768;
    for (int i = threadIdx.x; i < 1536; i += 384)
        ((float4*)xs)[i] = ((const float4*)xp)[i];
    __syncthreads();
    int wid = threadIdx.x >> 6, lane = threadIdx.x & 63;
    int sel = wid % 3, half = wid / 3;
    int hh = lane >> 4, dd = lane & 15;
    const float* W = sel == 0 ? wq : sel == 1 ? wk : wv;
    const float* Bb = sel == 0 ? bq : sel == 1 ? bk : bv;
    float wr[64];
#pragma unroll
    for (int f = 0; f < 64; ++f) wr[f] = W[f * 64 + lane];
    float bias = Bb[lane];
    for (int nl = half * 4; nl < half * 4 + 4; ++nl) {
        int n = n0 + nl;
        const float* xrow = xs + nl * 768;
        for (int t0 = 0; t0 < 12; t0 += 4) {
            float a[4] = {bias, bias, bias, bias};
#pragma unroll
            for (int f = 0; f < 64; ++f) {
                float w = wr[f];
                const float* xq = xrow + f * 12 + t0;
                a[0] = fmaf(xq[0], w, a[0]);
                a[1] = fmaf(xq[1], w, a[1]);
                a[2] = fmaf(xq[2], w, a[2]);
                a[3] = fmaf(xq[3], w, a[3]);
            }
#pragma unroll
            for (int i = 0; i < 4; ++i) {
                long bt = (long)b * 12 + t0 + i;
                sqkv[(((bt * 3 + sel) * NHc + hh) * Nc + n) * HDc + dd] = a[i];
            }
        }
    }
}

// ---------------- spatial attention: contiguous per-(bt,h) K/V slices, dbuf tiles ----------------
__global__ __launch_bounds__(448) void k_sattn3x(const float* __restrict__ sqkv,
                                                 float* __restrict__ Os) {
    constexpr int KT = 80;                      // 400 = 5*80
    __shared__ float Kb[2][KT * 16];
    __shared__ float Vb[2][KT * 16];
    int bth = blockIdx.x;
    int h = bth & 3;
    int bt = bth >> 2;
    const float* Qb = sqkv + (((long)bt * 3 + 0) * NHc + h) * (Nc * HDc);
    const float* Kg = sqkv + (((long)bt * 3 + 1) * NHc + h) * (Nc * HDc);
    const float* Vg = sqkv + (((long)bt * 3 + 2) * NHc + h) * (Nc * HDc);
    // prologue: stage tile 0 (fully contiguous float4 streams)
    for (int i = threadIdx.x; i < KT * 8; i += 448) {
        if (i < KT * 4) ((float4*)Kb[0])[i] = ((const float4*)Kg)[i];
        else            ((float4*)Vb[0])[i - KT * 4] = ((const float4*)Vg)[i - KT * 4];
    }
    int nq = threadIdx.x;
    float q[16];
    if (nq < Nc) {
        constexpr float SC = 0.25f * 1.44269504f;   // fold scale + log2(e)
#pragma unroll
        for (int d = 0; d < 16; ++d) q[d] = Qb[nq * 16 + d] * SC;
    }
    float m = -INFINITY, l = 0.f, acc[16];
#pragma unroll
    for (int d = 0; d < 16; ++d) acc[d] = 0.f;
    __syncthreads();
    for (int t = 0; t < 5; ++t) {
        int cur = t & 1;
        if (t < 4) {
            const float4* Kn = (const float4*)(Kg + (t + 1) * KT * 16);
            const float4* Vn = (const float4*)(Vg + (t + 1) * KT * 16);
            for (int i = threadIdx.x; i < KT * 8; i += 448) {
                if (i < KT * 4) ((float4*)Kb[cur ^ 1])[i] = Kn[i];
                else            ((float4*)Vb[cur ^ 1])[i - KT * 4] = Vn[i - KT * 4];
            }
        }
        if (nq < Nc) {
            for (int c = 0; c < KT; c += 16) {
                float s[16];
                float tm = -INFINITY;
#pragma unroll
                for (int kk = 0; kk < 16; ++kk) {
                    const float* kvp = &Kb[cur][(c + kk) * 16];
                    float d0 = 0.f;
#pragma unroll
                    for (int d = 0; d < 16; ++d) d0 = fmaf(q[d], kvp[d], d0);
                    s[kk] = d0;
                    tm = fmaxf(tm, d0);
                }
                if (tm > m) {
                    float corr = __builtin_amdgcn_exp2f(m - tm);
                    l *= corr;
#pragma unroll
                    for (int d = 0; d < 16; ++d) acc[d] *= corr;
                    m = tm;
                }
#pragma unroll
                for (int kk = 0; kk < 16; ++kk) {
                    float p = __builtin_amdgcn_exp2f(s[kk] - m);
                    l += p;
                    const float* vv = &Vb[cur][(c + kk) * 16];
#pragma unroll
                    for (int d = 0; d < 16; ++d) acc[d] = fmaf(p, vv[d], acc[d]);
                }
            }
        }
        __syncthreads();
    }
    if (nq < Nc) {
        float inv = 1.f / l;
        float* op = Os + ((long)bt * Nc + nq) * 64 + h * 16;
#pragma unroll
        for (int d = 0; d < 16; ++d) op[d] = acc[d] * inv;
    }
}

// ---------------- row-64 projection via wave-broadcast GEMM ----------------
__global__ __launch_bounds__(256) void k_proj64b(const float* __restrict__ X,
    const float* __restrict__ W, const float* __restrict__ bias,
    float* __restrict__ Y) {
    __shared__ float xs[64 * 64];
    long r0 = (long)blockIdx.x * 64;
    const float* xp = X + r0 * 64;
    for (int i = threadIdx.x; i < 1024; i += 256)
        ((float4*)xs)[i] = ((const float4*)xp)[i];
    int wid = threadIdx.x >> 6, lane = threadIdx.x & 63;
    float wr[64];
#pragma unroll
    for (int f = 0; f < 64; ++f) wr[f] = W[f * 64 + lane];
    float bv = bias[lane];
    __syncthreads();
    for (int g = 0; g < 4; ++g) {
        int r = wid * 16 + g * 4;
        float a[4] = {bv, bv, bv, bv};
#pragma unroll
        for (int f = 0; f < 64; ++f) {
            float w = wr[f];
            a[0] = fmaf(xs[(r + 0) * 64 + f], w, a[0]);
            a[1] = fmaf(xs[(r + 1) * 64 + f], w, a[1]);
            a[2] = fmaf(xs[(r + 2) * 64 + f], w, a[2]);
            a[3] = fmaf(xs[(r + 3) * 64 + f], w, a[3]);
        }
#pragma unroll
        for (int i = 0; i < 4; ++i) Y[(r0 + r + i) * 64 + lane] = a[i];
    }
}

// ---------------- dual no-bias projection: G1 = X@W1, G2 = X@W2 ----------------
__global__ __launch_bounds__(512) void k_proj2(const float* __restrict__ X,
    const float* __restrict__ W1, const float* __restrict__ W2,
    float* __restrict__ G1, float* __restrict__ G2) {
    __shared__ float xs[64 * 64];
    long r0 = (long)blockIdx.x * 64;
    const float* xp = X + r0 * 64;
    for (int i = threadIdx.x; i < 1024; i += 512)
        ((float4*)xs)[i] = ((const float4*)xp)[i];
    int wid = threadIdx.x >> 6, lane = threadIdx.x & 63;
    const float* W = (wid & 4) ? W2 : W1;
    float* G = (wid & 4) ? G2 : G1;
    int w4 = wid & 3;
    float wr[64];
#pragma unroll
    for (int f = 0; f < 64; ++f) wr[f] = W[f * 64 + lane];
    __syncthreads();
    for (int g = 0; g < 4; ++g) {
        int r = w4 * 16 + g * 4;
        float a[4] = {0.f, 0.f, 0.f, 0.f};
#pragma unroll
        for (int f = 0; f < 64; ++f) {
            float w = wr[f];
            a[0] = fmaf(xs[(r + 0) * 64 + f], w, a[0]);
            a[1] = fmaf(xs[(r + 1) * 64 + f], w, a[1]);
            a[2] = fmaf(xs[(r + 2) * 64 + f], w, a[2]);
            a[3] = fmaf(xs[(r + 3) * 64 + f], w, a[3]);
        }
#pragma unroll
        for (int i = 0; i < 4; ++i) G[(r0 + r + i) * 64 + lane] = a[i];
    }
}

// ---------------- sparse gather + sigmoid (no matmul, no LDS) ----------------
__global__ __launch_bounds__(256) void k_gath(const float* __restrict__ G1,
    const float* __restrict__ G2, const float* __restrict__ cf1,
    const float* __restrict__ cf2, const int* __restrict__ rowp,
    const int* __restrict__ dst, const float* __restrict__ thA,
    const float* __restrict__ thB, int E, float* __restrict__ Y) {
    int blk = blockIdx.x;
    int bt = blk % 192;
    int n0 = (blk / 192) * 4;
    int b = bt / Tc;
    int nl = threadIdx.x >> 6, lane = threadIdx.x & 63;
    int n = n0 + nl;
    const float* g1 = G1 + (long)bt * Nc * 64;
    const float* g2 = G2 + (long)bt * Nc * 64;
    const float* c1p = cf1 + (size_t)b * E;
    const float* c2p = cf2 + (size_t)b * E;
    int e0 = rowp[n], e1 = rowp[n + 1];
    float a1 = 0.f, a2 = 0.f;
    for (int e = e0; e < e1; ++e) {
        int j = dst[e] * 64 + lane;
        a1 = fmaf(c1p[e], g1[j], a1);
        a2 = fmaf(c2p[e], g2[j], a2);
    }
    float acc = thA[n] * a1 + thB[n] * a2;
    Y[((long)bt * Nc + n) * 64 + lane] = 1.f / (1.f + __expf(-acc));
}

// ---------------- temporal MHA: dedup scores, padded qs; ta in (B,N,T,F) ----------------
__global__ __launch_bounds__(384) void k_tattn3(const float* __restrict__ x,
    const float* __restrict__ wq, const float* __restrict__ bq,
    const float* __restrict__ wk, const float* __restrict__ bk,
    const float* __restrict__ wv, const float* __restrict__ bv,
    const float* __restrict__ wo, const float* __restrict__ bo,
    float* __restrict__ ta) {
    constexpr int QS = 193;
    __shared__ float xs_ol[3072];
    __shared__ float qs[48 * QS];
    float* xs = xs_ol;
    float* ol = xs_ol;
    int blk = blockIdx.x;
    int b = blk / 100, nch = blk % 100;
    int n0 = nch * 4;
    const float* xp = x + ((long)b * Nc + n0) * 768;
    for (int i = threadIdx.x; i < 768; i += 384)
        ((float4*)xs)[i] = ((const float4*)xp)[i];
    __syncthreads();
    int wid = threadIdx.x >> 6, lane = threadIdx.x & 63;
    {
        int sel = wid % 3, half = wid / 3;
        const float* W = sel == 0 ? wq : sel == 1 ? wk : wv;
        const float* Bb = sel == 0 ? bq : sel == 1 ? bk : bv;
        float wr[64];
#pragma unroll
        for (int f = 0; f < 64; ++f) wr[f] = W[f * 64 + lane];
        float bias = Bb[lane];
        for (int nl = half * 2; nl < half * 2 + 2; ++nl) {
            const float* xrow = xs + nl * 768;
            for (int t0 = 0; t0 < 12; t0 += 4) {
                float a[4] = {bias, bias, bias, bias};
#pragma unroll
                for (int f = 0; f < 64; ++f) {
                    float w = wr[f];
                    const float* xq = xrow + f * 12 + t0;
                    a[0] = fmaf(xq[0], w, a[0]);
                    a[1] = fmaf(xq[1], w, a[1]);
                    a[2] = fmaf(xq[2], w, a[2]);
                    a[3] = fmaf(xq[3], w, a[3]);
                }
#pragma unroll
                for (int i = 0; i < 4; ++i)
                    qs[(nl * 12 + t0 + i) * QS + sel * 64 + lane] = a[i];
            }
        }
    }
    __syncthreads();
    {
        int triple = threadIdx.x >> 1, dh = threadIdx.x & 1;
        int nl = triple / 48, r2 = triple % 48;
        int t = r2 >> 2, h = r2 & 3;
        const float* qv = qs + (nl * 12 + t) * QS + h * 16;
        float s[12];
        float mx = -INFINITY;
#pragma unroll
        for (int k = 0; k < 12; ++k) {
            const float* kv = qs + (nl * 12 + k) * QS + 64 + h * 16;
            float a0 = 0.f;
#pragma unroll
            for (int dd = 0; dd < 16; ++dd) a0 = fmaf(qv[dd], kv[dd], a0);
            s[k] = a0 * 0.25f;
            mx = fmaxf(mx, s[k]);
        }
        float l = 0.f;
#pragma unroll
        for (int k = 0; k < 12; ++k) { s[k] = __expf(s[k] - mx); l += s[k]; }
        float inv = 1.f / l;
#pragma unroll
        for (int dd = 0; dd < 8; ++dd) {
            int d = dh * 8 + dd;
            float o = 0.f;
#pragma unroll
            for (int k = 0; k < 12; ++k)
                o = fmaf(s[k], qs[(nl * 12 + k) * QS + 128 + h * 16 + d], o);
            ol[(nl * 12 + t) * 64 + h * 16 + d] = o * inv;
        }
    }
    __syncthreads();
    {
        float wr[64];
#pragma unroll
        for (int f = 0; f < 64; ++f) wr[f] = wo[f * 64 + lane];
        float ob = bo[lane];
        for (int g = 0; g < 2; ++g) {
            int r = wid * 8 + g * 4;
            float a[4] = {ob, ob, ob, ob};
#pragma unroll
            for (int f = 0; f < 64; ++f) {
                float w = wr[f];
                a[0] = fmaf(ol[(r + 0) * 64 + f], w, a[0]);
                a[1] = fmaf(ol[(r + 1) * 64 + f], w, a[1]);
                a[2] = fmaf(ol[(r + 2) * 64 + f], w, a[2]);
                a[3] = fmaf(ol[(r + 3) * 64 + f], w, a[3]);
            }
#pragma unroll
            for (int i = 0; i < 4; ++i) {
                int rr = r + i;
                int nl = rr / 12, t = rr % 12;
                ta[(((long)b * Nc + n0 + nl) * 12 + t) * 64 + lane] = a[i];
            }
        }
    }
}

// ---------------- neighborhood max (incl self); XCD-swizzled ----------------
__global__ __launch_bounds__(256) void k_segmax(const float* __restrict__ h,
    const int* __restrict__ rowp, const int* __restrict__ dst, float* __restrict__ Y) {
    int blk = blockIdx.x;
    int bt = blk % 192;
    int n0 = (blk / 192) * 4;
    int nl = threadIdx.x >> 6, f = threadIdx.x & 63;
    int n = n0 + nl;
    int e0 = rowp[n], e1 = rowp[n + 1];
    float m = -INFINITY;
    const float* hb = h + (long)bt * Nc * 64;
    for (int e = e0; e < e1; ++e) m = fmaxf(m, hb[dst[e] * 64 + f]);
    Y[((long)bt * Nc + n) * 64 + f] = m;
}

// ---------------- fused gated temporal conv + mask + residual relu + layernorm ----------------
__global__ __launch_bounds__(256) void k_gatedfinal(const float* __restrict__ ta,
    const float* __restrict__ tcw, const float* __restrict__ tcb,
    const float* __restrict__ gcw, const float* __restrict__ gcb,
    const float* __restrict__ mean2, const float* __restrict__ x,
    const float* __restrict__ mw, const float* __restrict__ md,
    const float* __restrict__ lng, const float* __restrict__ lnb,
    const int* __restrict__ maskp, float* __restrict__ out) {
    __shared__ float wl[192 * 65];       // [(ic*3+dt)*65 + o]
    __shared__ float tal[4][64 * 13];    // [ic*13 + t]
    int wave = threadIdx.x >> 6, lane = threadIdx.x & 63;
    int bn = blockIdx.x * 4 + wave;
    for (int idx = threadIdx.x; idx < 64 * 192; idx += 256) {
        int o = idx / 192, r = idx % 192;
        wl[r * 65 + o] = tcw[idx];
    }
    {
        const float* tr = ta + (long)bn * 768;
        for (int i = lane; i < 768; i += 64) {
            int t = i >> 6, f = i & 63;
            tal[wave][f * 13 + t] = tr[i];
        }
    }
    __syncthreads();
    int o = lane;
    float acc_t[12], acc_g[12];
#pragma unroll
    for (int t = 0; t < 12; ++t) acc_t[t] = tcb[o];
    for (int ic = 0; ic < 64; ++ic) {
        float xe[14];
        xe[0] = 0.f; xe[13] = 0.f;
#pragma unroll
        for (int t = 0; t < 12; ++t) xe[t + 1] = tal[wave][ic * 13 + t];
        float w0 = wl[(ic * 3 + 0) * 65 + o];
        float w1 = wl[(ic * 3 + 1) * 65 + o];
        float w2 = wl[(ic * 3 + 2) * 65 + o];
#pragma unroll
        for (int t = 0; t < 12; ++t)
            acc_t[t] += xe[t] * w0 + xe[t + 1] * w1 + xe[t + 2] * w2;
    }
    __syncthreads();
    for (int idx = threadIdx.x; idx < 64 * 192; idx += 256) {
        int o2 = idx / 192, r = idx % 192;
        wl[r * 65 + o2] = gcw[idx];
    }
    __syncthreads();
#pragma unroll
    for (int t = 0; t < 12; ++t) acc_g[t] = gcb[o];
    for (int ic = 0; ic < 64; ++ic) {
        float xe[14];
        xe[0] = 0.f; xe[13] = 0.f;
#pragma unroll
        for (int t = 0; t < 12; ++t) xe[t + 1] = tal[wave][ic * 13 + t];
        float w0 = wl[(ic * 3 + 0) * 65 + o];
        float w1 = wl[(ic * 3 + 1) * 65 + o];
        float w2 = wl[(ic * 3 + 2) * 65 + o];
#pragma unroll
        for (int t = 0; t < 12; ++t)
            acc_g[t] += xe[t] * w0 + xe[t + 1] * w1 + xe[t + 2] * w2;
    }
    int b = bn / Nc, n = bn % Nc;
    float maskf = maskp[0] ? (mw[bn] * md[bn]) : 1.f;
    const float* xrow = x + (long)bn * 768 + o * 12;   // (B,N,F,T): 12 contiguous t's
    float4 xa = *(const float4*)(xrow);
    float4 xb = *(const float4*)(xrow + 4);
    float4 xc = *(const float4*)(xrow + 8);
    float xv[12] = {xa.x, xa.y, xa.z, xa.w, xb.x, xb.y, xb.z, xb.w, xc.x, xc.y, xc.z, xc.w};
    float y[12];
#pragma unroll
    for (int t = 0; t < 12; ++t) {
        float g = acc_t[t] * (1.f / (1.f + __expf(-acc_g[t])));
        long base = ((long)(b * Tc + t) * Nc + n) * 64;
        float v = mean2[base + o] * maskf + g;
        float r = fmaxf(v + xv[t], 0.f);
        float s = r;
        for (int off = 32; off; off >>= 1) s += __shfl_xor(s, off, 64);
        float mu = s * (1.f / 64.f);
        float d = r - mu;
        float vs = d * d;
        for (int off = 32; off; off >>= 1) vs += __shfl_xor(vs, off, 64);
        float var = vs * (1.f / 64.f);
        y[t] = d * rsqrtf(var + 1e-5f) * lng[o] + lnb[o];
    }
    float* orow = out + (long)bn * 768 + o * 12;
    *(float4*)(orow)     = make_float4(y[0], y[1], y[2], y[3]);
    *(float4*)(orow + 4) = make_float4(y[4], y[5], y[6], y[7]);
    *(float4*)(orow + 8) = make_float4(y[8], y[9], y[10], y[11]);
}

extern "C" void kernel_launch(void* const* d_in, const int* in_sizes, int n_in,
                              void* d_out, int out_size, void* d_ws, size_t ws_size,
                              hipStream_t stream) {
    const float* x    = (const float*)d_in[0];
    const float* wadj = (const float*)d_in[1];
    const float* mw   = (const float*)d_in[2];
    const float* md   = (const float*)d_in[3];
    const float* th1  = (const float*)d_in[4];
    const float* th2  = (const float*)d_in[5];
    const float* th3  = (const float*)d_in[6];
    const float* th4  = (const float*)d_in[7];
    const float* gw1a = (const float*)d_in[8];
    const float* gw1b = (const float*)d_in[9];
    const float* gw2a = (const float*)d_in[10];
    const float* gw2b = (const float*)d_in[11];
    const float* mpw  = (const float*)d_in[12];
    const float* mpb  = (const float*)d_in[13];
    const float* tcw  = (const float*)d_in[14];
    const float* tcb  = (const float*)d_in[15];
    const float* gcw  = (const float*)d_in[16];
    const float* gcb  = (const float*)d_in[17];
    const float* sqw  = (const float*)d_in[18]; const float* sqb = (const float*)d_in[19];
    const float* skw  = (const float*)d_in[20]; const float* skb = (const float*)d_in[21];
    const float* svw  = (const float*)d_in[22]; const float* svb = (const float*)d_in[23];
    const float* sow  = (const float*)d_in[24]; const float* sob = (const float*)d_in[25];
    const float* tqw  = (const float*)d_in[26]; const float* tqb = (const float*)d_in[27];
    const float* tkw  = (const float*)d_in[28]; const float* tkb = (const float*)d_in[29];
    const float* tvw  = (const float*)d_in[30]; const float* tvb = (const float*)d_in[31];
    const float* tow  = (const float*)d_in[32]; const float* tob = (const float*)d_in[33];
    const float* lng  = (const float*)d_in[34]; const float* lnb = (const float*)d_in[35];
    const int* eidx   = (const int*)d_in[37];
    const int* maskp  = (const int*)d_in[38];
    int E = in_sizes[37] / 2;
    const int* esrc = eidx;
    const int* edst = eidx + E;

    const long SZ = (long)Bc * Tc * Nc * 64;             // 4,915,200
    float* ws = (float*)d_ws;
    // persistent region
    float* sqkv  = ws;                                   // [0,3SZ)
    float* Os    = ws + 3 * SZ;                          // [3SZ,4SZ); later mean2
    float* sa    = ws + 4 * SZ;
    float* ta    = ws + 5 * SZ;
    float* wadjT = ws + 6 * SZ;                          // B*N*N
    float* cf1   = wadjT + (long)Bc * NN;                // B*E
    float* cf2   = cf1 + (long)Bc * E;                   // B*E
    int*   rowp  = (int*)(cf2 + (long)Bc * E);           // N+1
    // phase aliases (sqkv region, dead after k_sattn3x)
    float* g1    = ws;
    float* g2    = ws + SZ;
    float* mean1 = ws + 2 * SZ;
    float* hbuf  = ws;                                   // after g1 dead
    float* maxp  = ws + SZ;                              // after g2 dead
    float* g1b   = ws;                                   // after hbuf dead
    float* g2b   = ws + 2 * SZ;                          // after mean1 dead
    float* mean2 = Os;                                   // Os dead after so-proj

    hipLaunchKernelGGL(k_rowptr, dim3(1), dim3(256), 0, stream, esrc, E, rowp);
    hipLaunchKernelGGL(k_transpose, dim3(13, 13, Bc), dim3(32, 8), 0, stream, wadj, wadjT);
    int w2blocks = (Bc * E + 3) / 4;
    hipLaunchKernelGGL(k_w2ec, dim3(w2blocks), dim3(256), 0, stream, wadj, wadjT, esrc, edst, rowp, E, cf1, cf2);
    hipLaunchKernelGGL(k_qkv3, dim3(Bc * 50), dim3(384), 0, stream, x, sqw, sqb, skw, skb, svw, svb, sqkv);
    hipLaunchKernelGGL(k_sattn3x, dim3(Bc * Tc * NHc), dim3(448), 0, stream, sqkv, Os);
    hipLaunchKernelGGL(k_proj64b, dim3(1200), dim3(256), 0, stream, Os, sow, sob, sa);
    hipLaunchKernelGGL(k_tattn3, dim3(Bc * 100), dim3(384), 0, stream, x, tqw, tqb, tkw, tkb, tvw, tvb, tow, tob, ta);
    hipLaunchKernelGGL(k_proj2, dim3(1200), dim3(512), 0, stream, sa, gw1a, gw1b, g1, g2);
    hipLaunchKernelGGL(k_gath, dim3(19200), dim3(256), 0, stream, g1, g2, cf1, cf2, rowp, edst, th1, th2, E, mean1);
    hipLaunchKernelGGL(k_proj64b, dim3(1200), dim3(256), 0, stream, mean1, mpw, mpb, hbuf);
    hipLaunchKernelGGL(k_segmax, dim3(19200), dim3(256), 0, stream, hbuf, rowp, edst, maxp);
    hipLaunchKernelGGL(k_proj2, dim3(1200), dim3(512), 0, stream, maxp, gw2a, gw2b, g1b, g2b);
    hipLaunchKernelGGL(k_gath, dim3(19200), dim3(256), 0, stream, g1b, g2b, cf1, cf2, rowp, edst, th3, th4, E, mean2);
    hipLaunchKernelGGL(k_gatedfinal, dim3(1600), dim3(256), 0, stream, ta, tcw, tcb, gcw, gcb,
                       mean2, x, mw, md, lng, lnb, maskp, (float*)d_out);
}